// Round 1
// baseline (252.616 us; speedup 1.0000x reference)
//
#include <hip/hip_runtime.h>

#define N_NODES 100000
#define N_RELS  2000
#define D       128
#define DEG     16

// Kernel 1: per-relation precompute.
// ws[r] = (inv_norm, att) where inv_norm = rsqrt(max(||rel_emb[r]||^2,1e-12)),
// att = exp(rel_emb[r] . attn_kernel)
__global__ __launch_bounds__(64) void rel_pre_kernel(
    const float* __restrict__ rel_emb,
    const float* __restrict__ attn,
    float2* __restrict__ ws) {
  const int r = blockIdx.x;
  const int lane = threadIdx.x;
  float2 ev = *(const float2*)(rel_emb + (size_t)r * D + lane * 2);
  float2 av = *(const float2*)(attn + lane * 2);
  float ss = ev.x * ev.x + ev.y * ev.y;
  float dt = ev.x * av.x + ev.y * av.y;
#pragma unroll
  for (int off = 32; off >= 1; off >>= 1) {
    ss += __shfl_xor(ss, off, 64);
    dt += __shfl_xor(dt, off, 64);
  }
  if (lane == 0) {
    float inv = rsqrtf(fmaxf(ss, 1e-12f));
    ws[r] = make_float2(inv, expf(dt));
  }
}

// Kernel 2: one wave per node. Lanes hold 2 feature dims each (float2).
// Edges of node n are triples rows 16n..16n+15 (subj = repeat(arange,16)),
// so the segment reduction is a private 16-iteration loop. No atomics.
__global__ __launch_bounds__(256) void gat_kernel(
    const int* __restrict__ triples,
    const float* __restrict__ features,
    const float* __restrict__ rel_emb,
    const float2* __restrict__ relws,
    float* __restrict__ out) {
  const int wave = threadIdx.x >> 6;
  const int lane = threadIdx.x & 63;
  const int node = blockIdx.x * 4 + wave;

  const int* t = triples + (size_t)node * DEG * 3;

  // Prefetch all 16 (rel,obj) index pairs so the dependent gathers can
  // issue early (index-load latency overlapped across the unrolled loop).
  int rels[DEG], objs[DEG];
#pragma unroll
  for (int i = 0; i < DEG; ++i) {
    rels[i] = t[3 * i + 1];
    objs[i] = t[3 * i + 2];
  }

  float2 acc = make_float2(0.f, 0.f);
  float den = 0.f;

#pragma unroll
  for (int i = 0; i < DEG; ++i) {
    // Indices are wave-uniform: push to SGPRs for scalar base addressing.
    const int rel = __builtin_amdgcn_readfirstlane(rels[i]);
    const int obj = __builtin_amdgcn_readfirstlane(objs[i]);

    float2 ov = *(const float2*)(features + (size_t)obj * D + lane * 2);
    float2 ev = *(const float2*)(rel_emb + (size_t)rel * D + lane * 2);
    float2 ia = relws[rel];  // (inv_norm, att)

    // dot(obj_emb, edge_emb) across the wave (lanes hold 2 dims each)
    float pd = ov.x * ev.x + ov.y * ev.y;
#pragma unroll
    for (int off = 32; off >= 1; off >>= 1) pd += __shfl_xor(pd, off, 64);

    // obj' = obj - 2*(dot(obj, edge_n)) * edge_emb ; edge_n = edge_emb*inv
    const float c = 2.f * pd * ia.x;
    const float att = ia.y;
    acc.x += att * (ov.x - c * ev.x);
    acc.y += att * (ov.y - c * ev.y);
    den += att;  // identical in every lane
  }

  float2 o = make_float2(acc.x / den, acc.y / den);
  *(float2*)(out + (size_t)node * D + lane * 2) = o;
}

extern "C" void kernel_launch(void* const* d_in, const int* in_sizes, int n_in,
                              void* d_out, int out_size, void* d_ws, size_t ws_size,
                              hipStream_t stream) {
  const int*   triples  = (const int*)d_in[0];
  const float* features = (const float*)d_in[1];
  const float* rel_emb  = (const float*)d_in[2];
  const float* attn     = (const float*)d_in[3];
  float*       out      = (float*)d_out;
  float2*      relws    = (float2*)d_ws;  // 2000 * 8 B

  rel_pre_kernel<<<N_RELS, 64, 0, stream>>>(rel_emb, attn, relws);
  gat_kernel<<<N_NODES / 4, 256, 0, stream>>>(triples, features, rel_emb, relws, out);
}

// Round 2
// 232.621 us; speedup vs baseline: 1.0860x; 1.0860x over previous
//
#include <hip/hip_runtime.h>

#define N_NODES 100000
#define N_RELS  2000
#define D       128
#define DEG     16

// Kernel 1: per-relation precompute.
// ws[r] = (inv_norm, att): inv_norm = rsqrt(max(||rel_emb[r]||^2,1e-12)),
// att = exp(rel_emb[r] . attn_kernel). 4 waves/block, 1 rel/wave.
__global__ __launch_bounds__(256) void rel_pre_kernel(
    const float* __restrict__ rel_emb,
    const float* __restrict__ attn,
    float2* __restrict__ ws) {
  const int wave = threadIdx.x >> 6;
  const int lane = threadIdx.x & 63;
  const int r = blockIdx.x * 4 + wave;
  float2 ev = *(const float2*)(rel_emb + (size_t)r * D + lane * 2);
  float2 av = *(const float2*)(attn + lane * 2);
  float ss = ev.x * ev.x + ev.y * ev.y;
  float dt = ev.x * av.x + ev.y * av.y;
#pragma unroll
  for (int off = 32; off >= 1; off >>= 1) {
    ss += __shfl_xor(ss, off, 64);
    dt += __shfl_xor(dt, off, 64);
  }
  if (lane == 0) {
    float inv = rsqrtf(fmaxf(ss, 1e-12f));
    ws[r] = make_float2(inv, expf(dt));
  }
}

// Kernel 2: one wave per node, 2 feature dims per lane (float2, coalesced).
// Edges of node n are triples rows 16n..16n+15 (subj = repeat(arange,16)),
// so segment_sum is a private 16-edge loop — no atomics.
//
// Structure for MLP: (1) one coalesced 192B load of the whole triples row,
// indices via readlane; (2) all 16 edges' gathers issued up-front;
// (3) acc = sum(att*ov) accumulated at load time (ov dies early),
//     reflection term -(2*att*inv*pd)*ev applied after 16 interleaved
//     shuffle-reduction chains (6 rounds x 16-way ILP).
__global__ __launch_bounds__(256) void gat_kernel(
    const int* __restrict__ triples,
    const float* __restrict__ features,
    const float* __restrict__ rel_emb,
    const float2* __restrict__ relws,
    float* __restrict__ out) {
  const int wave = threadIdx.x >> 6;
  const int lane = threadIdx.x & 63;
  const int node = blockIdx.x * 4 + wave;

  // Coalesced load of this node's 16 triples (48 ints = 192 B).
  const int* t = triples + (size_t)node * DEG * 3;
  int tv = (lane < DEG * 3) ? t[lane] : 0;

  float2 ev[DEG];
  float pd[DEG];     // per-lane partial dot(obj, edge)
  float cf[DEG];     // 2 * att * inv_norm
  float2 acc = make_float2(0.f, 0.f);
  float den = 0.f;

#pragma unroll
  for (int i = 0; i < DEG; ++i) {
    const int rel = __builtin_amdgcn_readfirstlane(__shfl(tv, 3 * i + 1, 64));
    const int obj = __builtin_amdgcn_readfirstlane(__shfl(tv, 3 * i + 2, 64));

    float2 ia = relws[rel];  // (inv_norm, att) — uniform addr -> scalar load
    float2 ov = *(const float2*)(features + (size_t)obj * D + lane * 2);
    float2 evi = *(const float2*)(rel_emb + (size_t)rel * D + lane * 2);

    pd[i] = ov.x * evi.x + ov.y * evi.y;
    const float att = ia.y;
    acc.x += att * ov.x;          // ov dead after this
    acc.y += att * ov.y;
    den += att;
    cf[i] = 2.f * att * ia.x;
    ev[i] = evi;
  }

  // 16 independent wave reductions, interleaved for ILP.
#pragma unroll
  for (int off = 32; off >= 1; off >>= 1) {
#pragma unroll
    for (int i = 0; i < DEG; ++i) pd[i] += __shfl_xor(pd[i], off, 64);
  }

#pragma unroll
  for (int i = 0; i < DEG; ++i) {
    const float c = cf[i] * pd[i];
    acc.x -= c * ev[i].x;
    acc.y -= c * ev[i].y;
  }

  const float r = 1.f / den;
  *(float2*)(out + (size_t)node * D + lane * 2) =
      make_float2(acc.x * r, acc.y * r);
}

extern "C" void kernel_launch(void* const* d_in, const int* in_sizes, int n_in,
                              void* d_out, int out_size, void* d_ws, size_t ws_size,
                              hipStream_t stream) {
  const int*   triples  = (const int*)d_in[0];
  const float* features = (const float*)d_in[1];
  const float* rel_emb  = (const float*)d_in[2];
  const float* attn     = (const float*)d_in[3];
  float*       out      = (float*)d_out;
  float2*      relws    = (float2*)d_ws;  // 2000 * 8 B

  rel_pre_kernel<<<N_RELS / 4, 256, 0, stream>>>(rel_emb, attn, relws);
  gat_kernel<<<N_NODES / 4, 256, 0, stream>>>(triples, features, rel_emb, relws, out);
}

// Round 3
// 174.445 us; speedup vs baseline: 1.4481x; 1.3335x over previous
//
#include <hip/hip_runtime.h>
#include <hip/hip_fp16.h>

#define N_NODES 100000
#define N_RELS  2000
#define D       128
#define DEG     16

// ws layout: [ relws: 2000*float2 (16KB, padded to 16384) | feat16 | rel16 ]
#define RELWS_BYTES  16384
#define FEAT16_BYTES ((size_t)N_NODES * D * 2)   // 25,600,000
#define REL16_BYTES  ((size_t)N_RELS * D * 2)    // 512,000
#define WS_NEED      (RELWS_BYTES + FEAT16_BYTES + REL16_BYTES)

static __device__ __forceinline__ __half2 bc_h2(unsigned int u) {
  return __builtin_bit_cast(__half2, u);
}

// ---------- per-relation precompute: (inv_norm, att) ----------
__global__ __launch_bounds__(256) void rel_pre_kernel(
    const float* __restrict__ rel_emb,
    const float* __restrict__ attn,
    float2* __restrict__ ws) {
  const int wave = threadIdx.x >> 6;
  const int lane = threadIdx.x & 63;
  const int r = blockIdx.x * 4 + wave;
  float2 ev = *(const float2*)(rel_emb + (size_t)r * D + lane * 2);
  float2 av = *(const float2*)(attn + lane * 2);
  float ss = ev.x * ev.x + ev.y * ev.y;
  float dt = ev.x * av.x + ev.y * av.y;
#pragma unroll
  for (int off = 32; off >= 1; off >>= 1) {
    ss += __shfl_xor(ss, off, 64);
    dt += __shfl_xor(dt, off, 64);
  }
  if (lane == 0) {
    float inv = rsqrtf(fmaxf(ss, 1e-12f));
    ws[r] = make_float2(inv, expf(dt));
  }
}

// ---------- fp32 -> fp16 compression (float4 -> 4 halves per thread) ----------
__global__ __launch_bounds__(256) void cvt_f32_f16_kernel(
    const float* __restrict__ src, uint2* __restrict__ dst) {
  const int i = blockIdx.x * 256 + threadIdx.x;  // float4 index
  float4 v = ((const float4*)src)[i];
  uint2 o;
  o.x = __builtin_bit_cast(unsigned int, __builtin_amdgcn_cvt_pkrtz(v.x, v.y));
  o.y = __builtin_bit_cast(unsigned int, __builtin_amdgcn_cvt_pkrtz(v.z, v.w));
  dst[i] = o;
}

// ---------- main kernel: 16 lanes per node, 4 nodes per wave ----------
// lane = g*16+s.  Lane (g,s) owns edge s of node g (indices, att, cf) AND
// dim-chunk s (8 halves) of node g's output.  Per iteration i: broadcast
// edge i's packed indices + (att,cf) within the 16-lane group (ds_bpermute),
// gather 8-dim fp16 fragments of O and E, packed-fp16 dot partial, 4-round
// butterfly for pd, packed-fp16 accumulate of att*ov - (cf*pd)*ev.
__global__ __launch_bounds__(256) void gat16_kernel(
    const int* __restrict__ triples,
    const unsigned short* __restrict__ feat16,
    const unsigned short* __restrict__ rel16,
    const float2* __restrict__ relws,
    float* __restrict__ out) {
  const int tid  = threadIdx.x;
  const int s    = tid & 15;
  const int wave = tid >> 6;
  const int g    = (tid >> 4) & 3;
  const int node = blockIdx.x * 16 + wave * 4 + g;

  // this lane's edge (node g, edge s)
  const int* t = triples + (size_t)node * (DEG * 3);
  const int tr = t[3 * s + 1];
  const int to = t[3 * s + 2];

  const float2 ia = relws[tr];       // (inv_norm, att)
  const float att = ia.y;
  const float cf  = 2.f * att * ia.x;

  // den = sum of att over the 16 edges of this group's node
  float den = att;
  den += __shfl_xor(den, 1);
  den += __shfl_xor(den, 2);
  den += __shfl_xor(den, 4);
  den += __shfl_xor(den, 8);
  const float rden = 1.f / den;

  // packed broadcast payloads: indices (to:17b | tr:11b), (att,cf) as 2xf16
  const int pidx = (to << 11) | tr;
  const int pattcf = __builtin_bit_cast(int, __builtin_amdgcn_cvt_pkrtz(att, cf));

  const int srcBase = tid & 48;  // first lane of my 16-lane group (wave-local)

  __half2 acc1[4], acc2[4];
#pragma unroll
  for (int j = 0; j < 4; ++j) {
    acc1[j] = __float2half2_rn(0.f);
    acc2[j] = __float2half2_rn(0.f);
  }

#pragma unroll
  for (int i = 0; i < DEG; ++i) {
    const int src = srcBase + i;
    const int p  = __shfl(pidx, src);
    const int ac = __shfl(pattcf, src);
    const int toi = p >> 11;
    const int tri = p & 2047;

    const uint4 of = *(const uint4*)(feat16 + (size_t)toi * D + s * 8);
    const uint4 ef = *(const uint4*)(rel16 + (size_t)tri * D + s * 8);
    const __half2 o0 = bc_h2(of.x), o1 = bc_h2(of.y), o2 = bc_h2(of.z), o3 = bc_h2(of.w);
    const __half2 e0 = bc_h2(ef.x), e1 = bc_h2(ef.y), e2 = bc_h2(ef.z), e3 = bc_h2(ef.w);

    // packed partial dot over this lane's 8 dims
    __half2 pp = __hmul2(o0, e0);
    pp = __hfma2(o1, e1, pp);
    pp = __hfma2(o2, e2, pp);
    pp = __hfma2(o3, e3, pp);
    float pd = __low2float(pp) + __high2float(pp);
    pd += __shfl_xor(pd, 1);
    pd += __shfl_xor(pd, 2);
    pd += __shfl_xor(pd, 4);
    pd += __shfl_xor(pd, 8);

    const __half2 h = bc_h2((unsigned int)ac);  // (att, cf)
    const __half2 att2 = __half2half2(__low2half(h));
    const __half2 c2 = __float2half2_rn(__high2float(h) * pd);

    acc1[0] = __hfma2(att2, o0, acc1[0]);
    acc1[1] = __hfma2(att2, o1, acc1[1]);
    acc1[2] = __hfma2(att2, o2, acc1[2]);
    acc1[3] = __hfma2(att2, o3, acc1[3]);
    acc2[0] = __hfma2(c2, e0, acc2[0]);
    acc2[1] = __hfma2(c2, e1, acc2[1]);
    acc2[2] = __hfma2(c2, e2, acc2[2]);
    acc2[3] = __hfma2(c2, e3, acc2[3]);
  }

  // epilogue: out[d] = (acc1 - acc2) / den, 8 fp32 dims per lane
  float* op = out + (size_t)node * D + s * 8;
  float4 r0, r1;
  {
    float2 a0 = __half22float2(acc1[0]), b0 = __half22float2(acc2[0]);
    float2 a1 = __half22float2(acc1[1]), b1 = __half22float2(acc2[1]);
    r0.x = (a0.x - b0.x) * rden; r0.y = (a0.y - b0.y) * rden;
    r0.z = (a1.x - b1.x) * rden; r0.w = (a1.y - b1.y) * rden;
    float2 a2 = __half22float2(acc1[2]), b2 = __half22float2(acc2[2]);
    float2 a3 = __half22float2(acc1[3]), b3 = __half22float2(acc2[3]);
    r1.x = (a2.x - b2.x) * rden; r1.y = (a2.y - b2.y) * rden;
    r1.z = (a3.x - b3.x) * rden; r1.w = (a3.y - b3.y) * rden;
  }
  *(float4*)op = r0;
  *(float4*)(op + 4) = r1;
}

// ---------- fallback (round-2 fp32 path) if ws is too small ----------
__global__ __launch_bounds__(256) void gat_kernel(
    const int* __restrict__ triples,
    const float* __restrict__ features,
    const float* __restrict__ rel_emb,
    const float2* __restrict__ relws,
    float* __restrict__ out) {
  const int wave = threadIdx.x >> 6;
  const int lane = threadIdx.x & 63;
  const int node = blockIdx.x * 4 + wave;
  const int* t = triples + (size_t)node * DEG * 3;
  int tv = (lane < DEG * 3) ? t[lane] : 0;
  float2 acc = make_float2(0.f, 0.f);
  float den = 0.f;
#pragma unroll
  for (int i = 0; i < DEG; ++i) {
    const int rel = __builtin_amdgcn_readfirstlane(__shfl(tv, 3 * i + 1, 64));
    const int obj = __builtin_amdgcn_readfirstlane(__shfl(tv, 3 * i + 2, 64));
    float2 ia = relws[rel];
    float2 ov = *(const float2*)(features + (size_t)obj * D + lane * 2);
    float2 ev = *(const float2*)(rel_emb + (size_t)rel * D + lane * 2);
    float pd = ov.x * ev.x + ov.y * ev.y;
#pragma unroll
    for (int off = 32; off >= 1; off >>= 1) pd += __shfl_xor(pd, off, 64);
    const float c = 2.f * pd * ia.x;
    const float att = ia.y;
    acc.x += att * (ov.x - c * ev.x);
    acc.y += att * (ov.y - c * ev.y);
    den += att;
  }
  const float r = 1.f / den;
  *(float2*)(out + (size_t)node * D + lane * 2) =
      make_float2(acc.x * r, acc.y * r);
}

extern "C" void kernel_launch(void* const* d_in, const int* in_sizes, int n_in,
                              void* d_out, int out_size, void* d_ws, size_t ws_size,
                              hipStream_t stream) {
  const int*   triples  = (const int*)d_in[0];
  const float* features = (const float*)d_in[1];
  const float* rel_emb  = (const float*)d_in[2];
  const float* attn     = (const float*)d_in[3];
  float*       out      = (float*)d_out;

  float2* relws = (float2*)d_ws;
  rel_pre_kernel<<<N_RELS / 4, 256, 0, stream>>>(rel_emb, attn, relws);

  if (ws_size >= WS_NEED) {
    unsigned short* feat16 = (unsigned short*)((char*)d_ws + RELWS_BYTES);
    unsigned short* rel16  = (unsigned short*)((char*)d_ws + RELWS_BYTES + FEAT16_BYTES);
    cvt_f32_f16_kernel<<<(N_NODES * D / 4) / 256, 256, 0, stream>>>(
        features, (uint2*)feat16);
    cvt_f32_f16_kernel<<<(N_RELS * D / 4) / 256, 256, 0, stream>>>(
        rel_emb, (uint2*)rel16);
    gat16_kernel<<<N_NODES / 16, 256, 0, stream>>>(
        triples, feat16, rel16, relws, out);
  } else {
    gat_kernel<<<N_NODES / 4, 256, 0, stream>>>(
        triples, features, rel_emb, relws, out);
  }
}

// Round 4
// 173.898 us; speedup vs baseline: 1.4527x; 1.0031x over previous
//
#include <hip/hip_runtime.h>
#include <hip/hip_fp16.h>

#define N_NODES 100000
#define N_RELS  2000
#define D       128
#define DEG     16

// ws layout: [ relws: 2000*float2 (padded to 16384B) | feat16 | rel16 ]
#define RELWS_BYTES  16384
#define FEAT16_BYTES ((size_t)N_NODES * D * 2)   // 25,600,000
#define REL16_BYTES  ((size_t)N_RELS * D * 2)    // 512,000
#define WS_NEED      (RELWS_BYTES + FEAT16_BYTES + REL16_BYTES)

static __device__ __forceinline__ __half2 bc_h2(unsigned int u) {
  return __builtin_bit_cast(__half2, u);
}
static __device__ __forceinline__ int bc_i(float f) {
  return __builtin_bit_cast(int, f);
}
static __device__ __forceinline__ float bc_f(int i) {
  return __builtin_bit_cast(float, i);
}

// Sum across each 16-lane row, result broadcast to all 16 lanes.
// 4 DPP row_shr adds (VALU pipe) leave the total in lane15 of each row;
// one ds_swizzle (and=0x10,or=0xF -> src=(lane&16)|15) broadcasts it.
static __device__ __forceinline__ float row16_sum_bcast(float v) {
  v += bc_f(__builtin_amdgcn_update_dpp(0, bc_i(v), 0x111, 0xF, 0xF, false)); // row_shr:1
  v += bc_f(__builtin_amdgcn_update_dpp(0, bc_i(v), 0x112, 0xF, 0xF, false)); // row_shr:2
  v += bc_f(__builtin_amdgcn_update_dpp(0, bc_i(v), 0x114, 0xF, 0xF, false)); // row_shr:4
  v += bc_f(__builtin_amdgcn_update_dpp(0, bc_i(v), 0x118, 0xF, 0xF, false)); // row_shr:8
  return bc_f(__builtin_amdgcn_ds_swizzle(bc_i(v), 0x1F0));                   // bcast lane15
}

// ---------- kernel 1: per-relation precompute + fp16 convert (fused) ----------
// relws[r] = (inv_norm, att); rel16[r] = fp16 row. One wave per relation.
__global__ __launch_bounds__(256) void rel_pre_kernel(
    const float* __restrict__ rel_emb,
    const float* __restrict__ attn,
    float2* __restrict__ relws,
    unsigned int* __restrict__ rel16u) {
  const int wave = threadIdx.x >> 6;
  const int lane = threadIdx.x & 63;
  const int r = blockIdx.x * 4 + wave;
  float2 ev = *(const float2*)(rel_emb + (size_t)r * D + lane * 2);
  float2 av = *(const float2*)(attn + lane * 2);
  rel16u[r * 64 + lane] =
      __builtin_bit_cast(unsigned int, __builtin_amdgcn_cvt_pkrtz(ev.x, ev.y));
  float ss = ev.x * ev.x + ev.y * ev.y;
  float dt = ev.x * av.x + ev.y * av.y;
#pragma unroll
  for (int off = 32; off >= 1; off >>= 1) {
    ss += __shfl_xor(ss, off, 64);
    dt += __shfl_xor(dt, off, 64);
  }
  if (lane == 0) {
    float inv = rsqrtf(fmaxf(ss, 1e-12f));
    relws[r] = make_float2(inv, expf(dt));
  }
}

// ---------- kernel 2: fp32 -> fp16 feature compression ----------
__global__ __launch_bounds__(256) void cvt_f32_f16_kernel(
    const float* __restrict__ src, uint2* __restrict__ dst) {
  const int i = blockIdx.x * 256 + threadIdx.x;  // float4 index
  float4 v = ((const float4*)src)[i];
  uint2 o;
  o.x = __builtin_bit_cast(unsigned int, __builtin_amdgcn_cvt_pkrtz(v.x, v.y));
  o.y = __builtin_bit_cast(unsigned int, __builtin_amdgcn_cvt_pkrtz(v.z, v.w));
  dst[i] = o;
}

// ---------- kernel 3: main. 16 lanes/node, 4 nodes/wave, 4 waves/block ----------
// lane (g,s): owns edge s of node g (indices/att/cf) AND dim-chunk s (8 halves)
// of node g's output. Edge records staged in LDS once; per iteration one
// broadcast ds_read_b64 replaces index shuffles. pd reduction: DPP + 1 swizzle.
// 8-deep explicit software pipeline on the of/ef gathers for MLP.
__global__ __launch_bounds__(256) void gat16_kernel(
    const int* __restrict__ triples,
    const unsigned short* __restrict__ feat16,
    const unsigned short* __restrict__ rel16,
    const float2* __restrict__ relws,
    float* __restrict__ out) {
  __shared__ uint2 recs[256];  // one edge record per thread

  const int tid  = threadIdx.x;
  const int s    = tid & 15;
  const int g    = (tid >> 4) & 3;
  const int wave = tid >> 6;
  const int node = blockIdx.x * 16 + wave * 4 + g;

  // This lane's edge (node g, edge s): indices + (att, cf).
  const int* t = triples + (size_t)node * (DEG * 3);
  const int tr = t[3 * s + 1];
  const int to = t[3 * s + 2];
  const float2 ia = relws[tr];  // (inv_norm, att)
  const float att = ia.y;
  const float cf  = 2.f * att * ia.x;

  // den over the 16 edges of this node (once).
  float den = att;
  den += __shfl_xor(den, 1);
  den += __shfl_xor(den, 2);
  den += __shfl_xor(den, 4);
  den += __shfl_xor(den, 8);
  const float rden = 1.f / den;

  // Stage edge record: idx packed (to:17b | tr:11b), (att,cf) as half2.
  recs[tid] = make_uint2(
      (unsigned int)((to << 11) | tr),
      __builtin_bit_cast(unsigned int, __builtin_amdgcn_cvt_pkrtz(att, cf)));
  __syncthreads();

  const int rbase = tid & 0xF0;  // wave*64 + g*16: first record of my node

  // 8-deep pipeline buffers.
  uint4 ofb[8], efb[8];
  unsigned int pacb[8];
#pragma unroll
  for (int i = 0; i < 8; ++i) {
    uint2 r = recs[rbase + i];
    pacb[i] = r.y;
    ofb[i] = *(const uint4*)(feat16 + (size_t)(r.x >> 11) * D + s * 8);
    efb[i] = *(const uint4*)(rel16 + (size_t)(r.x & 2047u) * D + s * 8);
  }

  __half2 acc1[4], acc2[4];
#pragma unroll
  for (int j = 0; j < 4; ++j) {
    acc1[j] = __float2half2_rn(0.f);
    acc2[j] = __float2half2_rn(0.f);
  }

#pragma unroll
  for (int i = 0; i < DEG; ++i) {
    const int j = i & 7;
    const uint4 of = ofb[j];
    const uint4 ef = efb[j];
    const unsigned int ac = pacb[j];
    if (i + 8 < DEG) {  // issue next gather into this slot before computing
      uint2 r = recs[rbase + i + 8];
      pacb[j] = r.y;
      ofb[j] = *(const uint4*)(feat16 + (size_t)(r.x >> 11) * D + s * 8);
      efb[j] = *(const uint4*)(rel16 + (size_t)(r.x & 2047u) * D + s * 8);
    }

    const __half2 o0 = bc_h2(of.x), o1 = bc_h2(of.y), o2 = bc_h2(of.z), o3 = bc_h2(of.w);
    const __half2 e0 = bc_h2(ef.x), e1 = bc_h2(ef.y), e2 = bc_h2(ef.z), e3 = bc_h2(ef.w);

    // partial dot over this lane's 8 dims, then row-wide sum+broadcast
    __half2 pp = __hmul2(o0, e0);
    pp = __hfma2(o1, e1, pp);
    pp = __hfma2(o2, e2, pp);
    pp = __hfma2(o3, e3, pp);
    const float pd = row16_sum_bcast(__low2float(pp) + __high2float(pp));

    const __half2 h = bc_h2(ac);  // (att, cf)
    const __half2 att2 = __half2half2(__low2half(h));
    const __half2 c2 = __float2half2_rn(__high2float(h) * pd);

    acc1[0] = __hfma2(att2, o0, acc1[0]);
    acc1[1] = __hfma2(att2, o1, acc1[1]);
    acc1[2] = __hfma2(att2, o2, acc1[2]);
    acc1[3] = __hfma2(att2, o3, acc1[3]);
    acc2[0] = __hfma2(c2, e0, acc2[0]);
    acc2[1] = __hfma2(c2, e1, acc2[1]);
    acc2[2] = __hfma2(c2, e2, acc2[2]);
    acc2[3] = __hfma2(c2, e3, acc2[3]);
  }

  // out[d] = (acc1 - acc2) / den for this lane's 8 dims
  float* op = out + (size_t)node * D + s * 8;
  float4 r0, r1;
  {
    float2 a0 = __half22float2(acc1[0]), b0 = __half22float2(acc2[0]);
    float2 a1 = __half22float2(acc1[1]), b1 = __half22float2(acc2[1]);
    r0.x = (a0.x - b0.x) * rden; r0.y = (a0.y - b0.y) * rden;
    r0.z = (a1.x - b1.x) * rden; r0.w = (a1.y - b1.y) * rden;
    float2 a2 = __half22float2(acc1[2]), b2 = __half22float2(acc2[2]);
    float2 a3 = __half22float2(acc1[3]), b3 = __half22float2(acc2[3]);
    r1.x = (a2.x - b2.x) * rden; r1.y = (a2.y - b2.y) * rden;
    r1.z = (a3.x - b3.x) * rden; r1.w = (a3.y - b3.y) * rden;
  }
  *(float4*)op = r0;
  *(float4*)(op + 4) = r1;
}

// ---------- fallback (fp32 path) if ws is too small ----------
__global__ __launch_bounds__(256) void gat_kernel(
    const int* __restrict__ triples,
    const float* __restrict__ features,
    const float* __restrict__ rel_emb,
    const float2* __restrict__ relws,
    float* __restrict__ out) {
  const int wave = threadIdx.x >> 6;
  const int lane = threadIdx.x & 63;
  const int node = blockIdx.x * 4 + wave;
  const int* t = triples + (size_t)node * DEG * 3;
  int tv = (lane < DEG * 3) ? t[lane] : 0;
  float2 acc = make_float2(0.f, 0.f);
  float den = 0.f;
#pragma unroll
  for (int i = 0; i < DEG; ++i) {
    const int rel = __builtin_amdgcn_readfirstlane(__shfl(tv, 3 * i + 1, 64));
    const int obj = __builtin_amdgcn_readfirstlane(__shfl(tv, 3 * i + 2, 64));
    float2 ia = relws[rel];
    float2 ov = *(const float2*)(features + (size_t)obj * D + lane * 2);
    float2 ev = *(const float2*)(rel_emb + (size_t)rel * D + lane * 2);
    float pd = ov.x * ev.x + ov.y * ev.y;
#pragma unroll
    for (int off = 32; off >= 1; off >>= 1) pd += __shfl_xor(pd, off, 64);
    const float c = 2.f * pd * ia.x;
    const float att = ia.y;
    acc.x += att * (ov.x - c * ev.x);
    acc.y += att * (ov.y - c * ev.y);
    den += att;
  }
  const float r = 1.f / den;
  *(float2*)(out + (size_t)node * D + lane * 2) =
      make_float2(acc.x * r, acc.y * r);
}

extern "C" void kernel_launch(void* const* d_in, const int* in_sizes, int n_in,
                              void* d_out, int out_size, void* d_ws, size_t ws_size,
                              hipStream_t stream) {
  const int*   triples  = (const int*)d_in[0];
  const float* features = (const float*)d_in[1];
  const float* rel_emb  = (const float*)d_in[2];
  const float* attn     = (const float*)d_in[3];
  float*       out      = (float*)d_out;

  float2* relws = (float2*)d_ws;

  if (ws_size >= WS_NEED) {
    unsigned short* feat16 = (unsigned short*)((char*)d_ws + RELWS_BYTES);
    unsigned int*   rel16u = (unsigned int*)((char*)d_ws + RELWS_BYTES + FEAT16_BYTES);
    rel_pre_kernel<<<N_RELS / 4, 256, 0, stream>>>(rel_emb, attn, relws, rel16u);
    cvt_f32_f16_kernel<<<(N_NODES * D / 4) / 256, 256, 0, stream>>>(
        features, (uint2*)feat16);
    gat16_kernel<<<N_NODES / 16, 256, 0, stream>>>(
        triples, feat16, (const unsigned short*)rel16u, relws, out);
  } else {
    rel_pre_kernel<<<N_RELS / 4, 256, 0, stream>>>(rel_emb, attn, relws,
                                                   (unsigned int*)d_ws);
    gat_kernel<<<N_NODES / 4, 256, 0, stream>>>(
        triples, features, rel_emb, relws, out);
  }
}